// Round 1
// baseline (1916.621 us; speedup 1.0000x reference)
//
#include <hip/hip_runtime.h>

// Gamma-smoothed forward-backward chain marginals, B=4 K=21 H=W=256.
// Linear-space recurrence: ea_new[k'] = (sum_k ea[k]*exp(p[k][k']/g)) * exp(u[k']/g),
// rescaled each step by the k=0 entry (scale cancels in final softmax).
// Scan kernel writes unnormalized ea (fwd) then ea*eb (bwd) into the mh/mv
// regions of d_out; combine kernel normalizes and emits all 4 outputs.

#define K 21
#define KP 22            // padded LDS row (8B-aligned rows, 2-way-free banks)
#define TT 8             // h-tile edges
#define HP 256
#define NE 255
#define ROWF (K*KP)      // 462
#define TILEF (TT*ROWF)  // 3696
#define EUF (TT*K)       // 168
#define NT 32            // ceil(255/8)
#define SZ (4*K*HP*HP)   // 5505024 floats per output tensor

__device__ __forceinline__ float rlane(float v, int l) {
  return __int_as_float(__builtin_amdgcn_readlane(__float_as_int(v), l));
}

__global__ __launch_bounds__(384)
void fp_scan_kernel(const float* __restrict__ uh, const float* __restrict__ uv,
                    const float* __restrict__ ph, const float* __restrict__ pv,
                    const float* __restrict__ gam, float* out) {
  __shared__ float smem[2*TILEF + 2*EUF];   // 30912 B; v-path uses first 672 floats
  const float g = fmaxf(gam[0], 0.01f);
  const float invg = 1.0f / g;
  float* outMH = out + 2L*SZ;
  float* outMV = out + 3L*SZ;
  const int wg = blockIdx.x;
  const int tid = threadIdx.x;

  if (wg < 64) {
    // ================= vertical chains: 16 chains/wg, coalesced direct loads ==========
    const int b   = wg >> 4;
    const int wc0 = (wg & 15) << 4;
    const int kIdx = tid >> 4;             // 0..23 (>=21 are clamped dups)
    const int c    = tid & 15;             // chain within group
    const int kk   = (kIdx < K) ? kIdx : (K-1);
    const bool pred = (kIdx < K);
    float* bc = smem;                      // 2 x 336 broadcast buffers

    const long uBase = ((long)(b*K + kk)*HP)*HP + wc0 + c;   // + i*HP
    const long kStep = (long)NE*HP;                           // per-k stride in pv

    float pA[K], pB[K];

    // ---------- forward ----------
    {
      const long pfBase = (((long)(b*K)*K + kk)*NE)*HP + wc0 + c;  // k=0,i=0 (thread owns k')
      float ea = __expf(uv[uBase] * invg);
      if (pred) outMV[uBase] = ea;
      #pragma unroll
      for (int k2 = 0; k2 < K; ++k2) pA[k2] = pv[pfBase + (long)k2*K*kStep];
      float uA = uv[uBase + 1L*HP], uB;

      auto fstep = [&](int i, const float* P, float uN, float ea_) -> float {
        bc[(i&1)*336 + kk*16 + c] = ea_;
        __syncthreads();
        const float* bb = bc + (i&1)*336 + c;
        float y0 = fmaxf(bb[0], 1e-33f);
        float s0=0.f, s1=0.f, s2=0.f;
        #pragma unroll
        for (int k2 = 0; k2 < K; k2 += 3) {
          s0 = fmaf(__expf(P[k2  ]*invg), bb[(k2  )*16], s0);
          s1 = fmaf(__expf(P[k2+1]*invg), bb[(k2+1)*16], s1);
          s2 = fmaf(__expf(P[k2+2]*invg), bb[(k2+2)*16], s2);
        }
        float r = (((s0+s1)+s2) / y0) * __expf(uN*invg);
        if (pred) outMV[uBase + (long)(i+1)*HP] = r;
        return r;
      };

      for (int i = 0; i < 254; i += 2) {          // depth-2 register prefetch
        #pragma unroll
        for (int k2=0;k2<K;++k2) pB[k2] = pv[pfBase + (long)k2*K*kStep + (long)(i+1)*HP];
        uB = uv[uBase + (long)(i+2)*HP];
        ea = fstep(i, pA, uA, ea);
        #pragma unroll
        for (int k2=0;k2<K;++k2) pA[k2] = pv[pfBase + (long)k2*K*kStep + (long)(i+2)*HP];
        uA = uv[uBase + (long)(i+3)*HP];
        ea = fstep(i+1, pB, uB, ea);
      }
      ea = fstep(254, pA, uA, ea);
    }
    __syncthreads();
    // ---------- backward ----------
    {
      const long pbBase = (((long)(b*K + kk)*K)*NE)*HP + wc0 + c;  // k'=0,i=0 (thread owns k)
      float eb = 1.0f;
      #pragma unroll
      for (int k2=0;k2<K;++k2) pA[k2] = pv[pbBase + (long)k2*kStep + 254L*HP];
      float uA  = uv[uBase + 255L*HP], uB;
      float eaA = outMV[uBase + 254L*HP], eaB;

      auto bstep = [&](int i, const float* P, float uN, float eaP, float eb_) -> float {
        float y = eb_ * __expf(uN*invg);
        bc[(i&1)*336 + kk*16 + c] = y;
        __syncthreads();
        const float* bb = bc + (i&1)*336 + c;
        float y0 = fmaxf(bb[0], 1e-33f);
        float s0=0.f, s1=0.f, s2=0.f;
        #pragma unroll
        for (int k2 = 0; k2 < K; k2 += 3) {
          s0 = fmaf(__expf(P[k2  ]*invg), bb[(k2  )*16], s0);
          s1 = fmaf(__expf(P[k2+1]*invg), bb[(k2+1)*16], s1);
          s2 = fmaf(__expf(P[k2+2]*invg), bb[(k2+2)*16], s2);
        }
        float r = ((s0+s1)+s2) / y0;
        if (pred) outMV[uBase + (long)i*HP] = eaP * r;   // unnormalized ea*eb
        return r;
      };

      for (int i = 254; i >= 2; i -= 2) {
        #pragma unroll
        for (int k2=0;k2<K;++k2) pB[k2] = pv[pbBase + (long)k2*kStep + (long)(i-1)*HP];
        uB  = uv[uBase + (long)i*HP];
        eaB = outMV[uBase + (long)(i-1)*HP];
        eb = bstep(i, pA, uA, eaA, eb);
        #pragma unroll
        for (int k2=0;k2<K;++k2) pA[k2] = pv[pbBase + (long)k2*kStep + (long)((i-2>0)?(i-2):0)*HP];
        uA  = uv[uBase + (long)(i-1)*HP];
        eaA = outMV[uBase + (long)((i-2>0)?(i-2):0)*HP];
        eb = bstep(i-1, pB, uB, eaB, eb);
      }
      eb = bstep(0, pA, uA, eaA, eb);
    }
  } else {
    // ================= horizontal chains: 1 chain/wg, LDS double-buffered tiles ======
    const int id = wg - 64;
    const int b = id >> 8;
    const int h = id & 255;
    const int lane   = tid & 63;
    const int waveId = tid >> 6;
    const int stid   = tid - 64;                  // staging thread id (waves 1..5)
    const int cc  = (lane < K) ? lane : (K-1);
    const bool act = (lane < K) && (waveId == 0);
    float* EuBase = smem + 2*TILEF;

    auto stage = [&](int it, int phase) {         // phase 0: [t][k'][k]; phase 1: [t][k][k']
      float* Pb = smem  + (it & 1)*TILEF;
      float* Eb = EuBase + (it & 1)*EUF;
      const int w0 = it * TT;
      for (int idx = stid; idx < 3696; idx += 320) {
        if (idx < 3528) {
          int row = idx >> 3, t = idx & 7;
          int k = row / K, kp = row - k*K;
          int w = min(w0 + t, NE-1);
          float val = ph[(((long)(b*K + k)*K + kp)*HP + h)*(long)NE + w];
          float e = __expf(val * invg);
          int a  = phase ? k : kp;
          int b2 = phase ? kp : k;
          Pb[t*ROWF + a*KP + b2] = e;
        } else {
          int r = idx - 3528;
          int kk2 = r >> 3, t = r & 7;
          int pos = min(w0 + 1 + t, HP-1);
          float val = uh[((long)(b*K + kk2)*HP + h)*HP + pos];
          Eb[t*K + kk2] = __expf(val * invg);
        }
      }
    };

    const long chanBase = ((long)(b*K + cc)*HP + h)*HP;   // + w

    // ---------- forward ----------
    float ea = 0.f;
    if (waveId == 0) {
      ea = __expf(uh[chanBase] * invg);          // position 0
      if (act) outMH[chanBase] = ea;
    }
    if (waveId > 0) stage(0, 0);
    __syncthreads();
    for (int it = 0; it < NT; ++it) {
      if (waveId > 0) {
        if (it + 1 < NT) stage(it + 1, 0);
      } else {
        float* Pb = smem  + (it & 1)*TILEF;
        float* Eb = EuBase + (it & 1)*EUF;
        const int w0 = it * TT;
        const int tt = min(TT, NE - w0);
        for (int t = 0; t < tt; ++t) {
          const float* row = Pb + t*ROWF + cc*KP;
          float s0=0.f, s1=0.f, s2=0.f;
          #pragma unroll
          for (int k2 = 0; k2 < K; k2 += 3) {
            s0 = fmaf(row[k2  ], rlane(ea, k2  ), s0);
            s1 = fmaf(row[k2+1], rlane(ea, k2+1), s1);
            s2 = fmaf(row[k2+2], rlane(ea, k2+2), s2);
          }
          float v  = ((s0+s1)+s2) * Eb[t*K + cc];
          float v0 = fmaxf(rlane(v, 0), 1e-33f);
          ea = v / v0;
          if (act) outMH[chanBase + (w0 + t + 1)] = ea;
        }
      }
      __syncthreads();
    }
    // ---------- backward ----------
    float eb = 1.0f;
    float eaPref = 0.f;
    if (waveId == 0) eaPref = outMH[chanBase + (NE-1)];   // ea at pos 254
    if (waveId > 0) stage(NT-1, 1);
    __syncthreads();
    for (int it = NT-1; it >= 0; --it) {
      if (waveId > 0) {
        if (it > 0) stage(it - 1, 1);
      } else {
        float* Pb = smem  + (it & 1)*TILEF;
        float* Eb = EuBase + (it & 1)*EUF;
        const int w0 = it * TT;
        const int tt = min(TT, NE - w0);
        for (int t = tt - 1; t >= 0; --t) {
          float y = eb * Eb[t*K + cc];
          const float* row = Pb + t*ROWF + cc*KP;
          float s0=0.f, s1=0.f, s2=0.f;
          #pragma unroll
          for (int k2 = 0; k2 < K; k2 += 3) {
            s0 = fmaf(row[k2  ], rlane(y, k2  ), s0);
            s1 = fmaf(row[k2+1], rlane(y, k2+1), s1);
            s2 = fmaf(row[k2+2], rlane(y, k2+2), s2);
          }
          float s  = (s0+s1)+s2;
          float v0 = fmaxf(rlane(s, 0), 1e-33f);
          eb = s / v0;
          float prod = eaPref * eb;
          int pos = w0 + t;
          eaPref = outMH[chanBase + max(pos - 1, 0)];   // prefetch next (lower) position
          if (act) outMH[chanBase + pos] = prod;
        }
      }
      __syncthreads();
    }
  }
}

__global__ __launch_bounds__(256)
void fp_combine_kernel(const float* __restrict__ uh, const float* __restrict__ uv,
                       float* __restrict__ out) {
  const int lin = blockIdx.x * 256 + threadIdx.x;   // B*H*W = 262144 exactly
  const int b   = lin >> 16;
  const int rem = lin & 65535;                       // h*256 + w
  const long base = (long)b * K * 65536 + rem;
  const long KS = 65536;
  float mh[K], mv[K];
  float smh = 0.f, smv = 0.f;
  #pragma unroll
  for (int k = 0; k < K; ++k) {
    mh[k] = out[2L*SZ + base + k*KS];
    mv[k] = out[3L*SZ + base + k*KS];
    smh += mh[k]; smv += mv[k];
  }
  const float rh = 1.0f / smh, rv = 1.0f / smv;
  #pragma unroll
  for (int k = 0; k < K; ++k) {
    float a  = mh[k] * rh;        // normalized mh
    float vv = mv[k] * rv;        // normalized mv
    float d  = (a - vv) * (1.0f / 512.0f);   // (mh-avg)/W = (mh-mv)/(2*256)
    out[        base + k*KS] = uh[base + k*KS] - d;
    out[1L*SZ + base + k*KS] = uv[base + k*KS] + d;
    out[2L*SZ + base + k*KS] = a;
    out[3L*SZ + base + k*KS] = vv;
  }
}

extern "C" void kernel_launch(void* const* d_in, const int* in_sizes, int n_in,
                              void* d_out, int out_size, void* d_ws, size_t ws_size,
                              hipStream_t stream) {
  const float* uh = (const float*)d_in[0];
  const float* uv = (const float*)d_in[1];
  const float* ph = (const float*)d_in[2];
  const float* pv = (const float*)d_in[3];
  const float* gm = (const float*)d_in[4];
  float* out = (float*)d_out;
  hipLaunchKernelGGL(fp_scan_kernel,    dim3(1088), dim3(384), 0, stream, uh, uv, ph, pv, gm, out);
  hipLaunchKernelGGL(fp_combine_kernel, dim3(1024), dim3(256), 0, stream, uh, uv, out);
}